// Round 1
// baseline (913.813 us; speedup 1.0000x reference)
//
#include <hip/hip_runtime.h>
#include <math.h>

// Decode paged attention, flash-decoding split-K.
// B=32, Hq=32, Hkv=8, G=4, D=128, page=16, max_pages=256 (T<=4096), fp32.

#define NUM_B    32
#define HQ       32
#define HKV      8
#define GG       4
#define DD       128
#define PAGE     16
#define MAXPAGES 256
#define SPLITS   16
#define CHUNK    256   // tokens per split (16 pages)

static constexpr float SCALE_F = 0.08838834764831845f; // 1/sqrt(128)
static constexpr float NEG     = -1e30f;               // finite -inf sentinel (avoids exp(nan))

static __device__ __forceinline__ float dot8(const float4& qa, const float4& qb,
                                             const float4& ka, const float4& kb) {
    return qa.x * ka.x + qa.y * ka.y + qa.z * ka.z + qa.w * ka.w +
           qb.x * kb.x + qb.y * kb.y + qb.z * kb.z + qb.w * kb.w;
}

// One wave per (b, kvh, split). Wave = 4 token-groups x 16 lanes.
// Lane (tg, ds): handles token tb+tg, D-slice [8*ds, 8*ds+8).
__global__ __launch_bounds__(64) void attn_split_kernel(
    const float* __restrict__ q,        // [B,1,HQ,DD]
    const float* __restrict__ kc,       // [8192,PAGE,HKV,DD]
    const float* __restrict__ vc,       // [8192,PAGE,HKV,DD]
    const int*   __restrict__ seqlens,  // [B]
    const int*   __restrict__ btab,     // [B,MAXPAGES]
    float*       __restrict__ accW,     // [B][HKV][SPLITS][GG][DD]
    float*       __restrict__ mlW)      // [B][HKV][SPLITS][GG][2]
{
    const int bid   = blockIdx.x;
    const int split = bid & (SPLITS - 1);
    const int kvh   = (bid >> 4) & (HKV - 1);
    const int b     = bid >> 7;
    const int lane  = threadIdx.x;   // 0..63
    const int tg    = lane >> 4;     // token-group 0..3
    const int ds    = lane & 15;     // D sub-slice 0..15

    const long pbase   = ((long)(b * HKV + kvh) * SPLITS + split) * GG;
    const long accBase = pbase * DD;
    const long mlBase  = pbase * 2;

    const int T  = seqlens[b];
    const int t0 = split * CHUNK;

    if (t0 >= T) {
        // Empty partial: m=NEG, l=0, acc=0 (reducer weight = exp(NEG-M) = 0).
        if (tg == 0) {
            const float4 z = make_float4(0.f, 0.f, 0.f, 0.f);
            #pragma unroll
            for (int g = 0; g < GG; ++g) {
                *(float4*)(accW + accBase + g * DD + ds * 8)     = z;
                *(float4*)(accW + accBase + g * DD + ds * 8 + 4) = z;
            }
            if (ds == 0) {
                #pragma unroll
                for (int g = 0; g < GG; ++g) {
                    mlW[mlBase + g * 2]     = NEG;
                    mlW[mlBase + g * 2 + 1] = 0.f;
                }
            }
        }
        return;
    }

    const int t1 = min(T, t0 + CHUNK);

    // Q fragments: q[b, 0, kvh*G+g, 8*ds .. 8*ds+8)
    float4 q0[GG], q1[GG];
    #pragma unroll
    for (int g = 0; g < GG; ++g) {
        const float* qp = q + (long)(b * HQ + kvh * GG + g) * DD + ds * 8;
        q0[g] = *(const float4*)qp;
        q1[g] = *(const float4*)(qp + 4);
    }

    float m[GG], l[GG], acc[GG][8];
    #pragma unroll
    for (int g = 0; g < GG; ++g) {
        m[g] = NEG;
        l[g] = 0.f;
        #pragma unroll
        for (int j = 0; j < 8; ++j) acc[g][j] = 0.f;
    }

    const int btab_b = b * MAXPAGES;
    auto load_kv = [&](int tb, float4& k0, float4& k1, float4& v0, float4& v1) {
        const int t = min(tb + tg, t1 - 1);             // address-clamp; always in-bounds
        const int page = btab[btab_b + (t >> 4)];
        const long off = (((long)page * PAGE + (t & 15)) * HKV + kvh) * DD + ds * 8;
        k0 = *(const float4*)(kc + off);
        k1 = *(const float4*)(kc + off + 4);
        v0 = *(const float4*)(vc + off);
        v1 = *(const float4*)(vc + off + 4);
    };

    float4 k0, k1, v0, v1;
    load_kv(t0, k0, k1, v0, v1);

    for (int tb = t0; tb < t1; tb += 4) {
        const bool valid = (tb + tg) < t1;
        const float4 ck0 = k0, ck1 = k1, cv0 = v0, cv1 = v1;
        load_kv(tb + 4, k0, k1, v0, v1);   // prefetch next (clamped; last iter redundant)

        #pragma unroll
        for (int g = 0; g < GG; ++g) {
            float s = dot8(q0[g], q1[g], ck0, ck1);
            s += __shfl_xor(s, 1);
            s += __shfl_xor(s, 2);
            s += __shfl_xor(s, 4);
            s += __shfl_xor(s, 8);
            s = valid ? s * SCALE_F : NEG;
            const float mn    = fmaxf(m[g], s);
            const float alpha = __expf(m[g] - mn);     // finite-finite: no NaN
            const float p     = valid ? __expf(s - mn) : 0.f;
            l[g] = l[g] * alpha + p;
            m[g] = mn;
            acc[g][0] = acc[g][0] * alpha + p * cv0.x;
            acc[g][1] = acc[g][1] * alpha + p * cv0.y;
            acc[g][2] = acc[g][2] * alpha + p * cv0.z;
            acc[g][3] = acc[g][3] * alpha + p * cv0.w;
            acc[g][4] = acc[g][4] * alpha + p * cv1.x;
            acc[g][5] = acc[g][5] * alpha + p * cv1.y;
            acc[g][6] = acc[g][6] * alpha + p * cv1.z;
            acc[g][7] = acc[g][7] * alpha + p * cv1.w;
        }
    }

    // Merge the 4 token-group states (lanes differing in bits 4..5) and store one partial.
    #pragma unroll
    for (int g = 0; g < GG; ++g) {
        float M2 = m[g];
        M2 = fmaxf(M2, __shfl_xor(M2, 16));
        M2 = fmaxf(M2, __shfl_xor(M2, 32));
        const float alpha = __expf(m[g] - M2);  // empty tg: exp(NEG-M2)=0
        float lg = l[g] * alpha;
        lg += __shfl_xor(lg, 16);
        lg += __shfl_xor(lg, 32);
        float a[8];
        #pragma unroll
        for (int j = 0; j < 8; ++j) {
            float x = acc[g][j] * alpha;
            x += __shfl_xor(x, 16);
            x += __shfl_xor(x, 32);
            a[j] = x;
        }
        if (tg == 0) {
            const float4 o0 = make_float4(a[0], a[1], a[2], a[3]);
            const float4 o1 = make_float4(a[4], a[5], a[6], a[7]);
            *(float4*)(accW + accBase + g * DD + ds * 8)     = o0;
            *(float4*)(accW + accBase + g * DD + ds * 8 + 4) = o1;
            if (ds == 0) {
                mlW[mlBase + g * 2]     = M2;
                mlW[mlBase + g * 2 + 1] = lg;
            }
        }
    }
}

// Combine SPLITS partials per (b, kvh, g). One block per (b,kvh,g), 128 threads (d).
__global__ __launch_bounds__(128) void attn_reduce_kernel(
    const float* __restrict__ accW,
    const float* __restrict__ mlW,
    float*       __restrict__ out)   // [B, HQ, DD]
{
    const int bid = blockIdx.x;          // B*HKV*GG = 1024
    const int g   = bid & 3;
    const int kvh = (bid >> 2) & 7;
    const int b   = bid >> 5;
    const int d   = threadIdx.x;

    const long base = (long)(b * HKV + kvh) * SPLITS * GG;

    float ms[SPLITS], ls[SPLITS];
    float M = NEG;
    #pragma unroll
    for (int s = 0; s < SPLITS; ++s) {
        ms[s] = mlW[(base + s * GG + g) * 2];
        ls[s] = mlW[(base + s * GG + g) * 2 + 1];
        M = fmaxf(M, ms[s]);
    }
    float L = 0.f, o = 0.f;
    #pragma unroll
    for (int s = 0; s < SPLITS; ++s) {
        const float w = __expf(ms[s] - M);   // split 0 always non-empty -> M finite, L > 0
        L += ls[s] * w;
        o += w * accW[(base + s * GG + g) * DD + d];
    }
    out[(long)(b * HQ + kvh * GG + g) * DD + d] = o / L;
}

extern "C" void kernel_launch(void* const* d_in, const int* in_sizes, int n_in,
                              void* d_out, int out_size, void* d_ws, size_t ws_size,
                              hipStream_t stream)
{
    const float* q       = (const float*)d_in[0];
    const float* kc      = (const float*)d_in[1];
    const float* vc      = (const float*)d_in[2];
    const int*   seqlens = (const int*)d_in[3];
    const int*   btab    = (const int*)d_in[4];
    float*       out     = (float*)d_out;

    // Workspace: acc partials (8 MB) + m/l partials (256 KB). Needs ~8.7 MB.
    float* accW = (float*)d_ws;
    float* mlW  = accW + (size_t)NUM_B * HKV * SPLITS * GG * DD;

    attn_split_kernel<<<NUM_B * HKV * SPLITS, 64, 0, stream>>>(
        q, kc, vc, seqlens, btab, accW, mlW);
    attn_reduce_kernel<<<NUM_B * HKV * GG, DD, 0, stream>>>(accW, mlW, out);
}